// Round 10
// baseline (9047.727 us; speedup 1.0000x reference)
//
#include <hip/hip_runtime.h>

typedef unsigned short u16;
typedef unsigned int u32;
typedef unsigned long long u64;
typedef __bf16 bf16x8 __attribute__((ext_vector_type(8)));
typedef float f32x4 __attribute__((ext_vector_type(4)));

union FU { f32x4 f; bf16x8 h; };

__device__ __forceinline__ u16 f2b(float f) {
  unsigned u = __float_as_uint(f);
  return (u16)((u + 0x7fffu + ((u >> 16) & 1u)) >> 16);
}

// per-lane coherent 2B store (init only; cold path)
__device__ __forceinline__ void st_b16_llc(u16* p, u16 v) {
  __hip_atomic_store(p, v, __ATOMIC_RELAXED, __HIP_MEMORY_SCOPE_AGENT);
}

// plain coherent stores (wave-coalesced; no TCC atomic serialization)
__device__ __forceinline__ void st_u32_cc(u32* p, u32 v) {
  asm volatile("global_store_dword %0, %1, off sc0 sc1" :: "v"(p), "v"(v) : "memory");
}
__device__ __forceinline__ void st_u64_cc(void* p, u64 v) {
  asm volatile("global_store_dwordx2 %0, %1, off sc0 sc1" :: "v"(p), "v"(v) : "memory");
}

// coherent dwordx4 load (poll path; valid on return)
__device__ __forceinline__ uint4 ld_poll4(const u32* p) {
  uint4 v;
  asm volatile("global_load_dwordx4 %0, %1, off sc0 sc1\n\ts_waitcnt vmcnt(0)"
               : "=v"(v) : "v"(p) : "memory");
  return v;
}

// pack 4 neighboring lanes' bf16 into one u64 (lanes c15&3==0 hold cols +0..3)
// partners (xor 1, xor 2) stay inside the active 8-lane publish group.
__device__ __forceinline__ u64 pack4(u32 lo) {
  u32 p2 = lo | ((u32)__shfl_xor((int)lo, 1) << 16);
  return (u64)p2 | ((u64)(u32)__shfl_xor((int)p2, 2) << 32);
}

// issue 8 coherent 16B loads (covers 8 k-steps = 256 u16); valid after WAITV
#define ISSUE8CC(D, P)                                                       \
  asm volatile(                                                              \
      "global_load_dwordx4 %0, %8, off sc0 sc1\n\t"                          \
      "global_load_dwordx4 %1, %8, off offset:64 sc0 sc1\n\t"                \
      "global_load_dwordx4 %2, %8, off offset:128 sc0 sc1\n\t"               \
      "global_load_dwordx4 %3, %8, off offset:192 sc0 sc1\n\t"               \
      "global_load_dwordx4 %4, %8, off offset:256 sc0 sc1\n\t"               \
      "global_load_dwordx4 %5, %8, off offset:320 sc0 sc1\n\t"               \
      "global_load_dwordx4 %6, %8, off offset:384 sc0 sc1\n\t"               \
      "global_load_dwordx4 %7, %8, off offset:448 sc0 sc1"                   \
      : "=&v"((D)[0].f), "=&v"((D)[1].f), "=&v"((D)[2].f), "=&v"((D)[3].f),  \
        "=&v"((D)[4].f), "=&v"((D)[5].f), "=&v"((D)[6].f), "=&v"((D)[7].f)   \
      : "v"(P) : "memory")

// issue 4 cached 16B loads (read-only x data; counted in vmcnt like the rest)
#define ISSUE4C(D, P)                                                        \
  asm volatile(                                                              \
      "global_load_dwordx4 %0, %4, off\n\t"                                  \
      "global_load_dwordx4 %1, %4, off offset:64\n\t"                        \
      "global_load_dwordx4 %2, %4, off offset:128\n\t"                       \
      "global_load_dwordx4 %3, %4, off offset:192"                           \
      : "=&v"((D)[0].f), "=&v"((D)[1].f), "=&v"((D)[2].f), "=&v"((D)[3].f)   \
      : "v"(P) : "memory")

// counted wait + hard scheduling fence (rule #18: consumers stay below)
#define WAITV(N)                                                             \
  do {                                                                       \
    asm volatile("s_waitcnt vmcnt(" #N ")" ::: "memory");                    \
    __builtin_amdgcn_sched_barrier(0);                                       \
  } while (0)

// 8 MFMAs: A-frags from BUF, B-frags from LDS (zr layout / g layout)
#define MFMA8ZR(ACC, BUF, KSB)                                               \
  do {                                                                       \
    _Pragma("unroll") for (int j_ = 0; j_ < 8; ++j_)                         \
        ACC = __builtin_amdgcn_mfma_f32_16x16x32_bf16(                       \
            (BUF)[j_].h,                                                     \
            *(const bf16x8*)&zr_frag[(KSB + j_) * 512 + lane * 8],           \
            ACC, 0, 0, 0);                                                   \
  } while (0)
#define MFMA8G(ACC, BUF, KSB)                                                \
  do {                                                                       \
    _Pragma("unroll") for (int j_ = 0; j_ < 8; ++j_)                         \
        ACC = __builtin_amdgcn_mfma_f32_16x16x32_bf16(                       \
            (BUF)[j_].h,                                                     \
            *(const bf16x8*)&g_frag[(KSB + j_) * 256 + boff],                \
            ACC, 0, 0, 0);                                                   \
  } while (0)

// ---------------- generic fp32 -> bf16 cast ----------------
__global__ void cast_f32_bf16(const float* __restrict__ in, u16* __restrict__ out, int n) {
  int i = blockIdx.x * 256 + threadIdx.x;
  if (i < n) out[i] = f2b(in[i]);
}

// ---------------- tiled bf16 GEMM: C[M,N] = A[M,K] @ B[N,K]^T (fp32 out) ----------------
__global__ __launch_bounds__(256) void gemm_bt(
    const u16* __restrict__ A, const u16* __restrict__ B,
    int M, int N, int K,
    const float* __restrict__ bias, float* __restrict__ Cf)
{
  __shared__ u16 a_sm[128 * 32];
  __shared__ u16 b_sm[128 * 32];
  const int tid = threadIdx.x;
  const int lane = tid & 63;
  const int wid = tid >> 6;
  const int wm = wid >> 1, wn = wid & 1;
  const int m0 = blockIdx.x * 128, n0 = blockIdx.y * 128;
  const int q = lane >> 4, l15 = lane & 15, l3 = lane & 3;

  f32x4 acc[4][4];
  #pragma unroll
  for (int i = 0; i < 4; ++i)
    #pragma unroll
    for (int j = 0; j < 4; ++j) acc[i][j] = (f32x4){0.f, 0.f, 0.f, 0.f};

  for (int kk = 0; kk < K; kk += 32) {
    __syncthreads();
    #pragma unroll
    for (int p = 0; p < 2; ++p) {
      int idx = p * 256 + tid;
      int r = idx >> 2, cch = idx & 3;
      *(uint4*)&a_sm[r * 32 + ((cch ^ (r & 3)) * 8)] =
          *(const uint4*)&A[(size_t)(m0 + r) * K + kk + cch * 8];
      *(uint4*)&b_sm[r * 32 + ((cch ^ (r & 3)) * 8)] =
          *(const uint4*)&B[(size_t)(n0 + r) * K + kk + cch * 8];
    }
    __syncthreads();
    bf16x8 af[4], bfr[4];
    #pragma unroll
    for (int s = 0; s < 4; ++s) {
      int ra = wm * 64 + s * 16 + l15;
      af[s] = *(const bf16x8*)&a_sm[ra * 32 + ((q ^ l3) * 8)];
      int rb = wn * 64 + s * 16 + l15;
      bfr[s] = *(const bf16x8*)&b_sm[rb * 32 + ((q ^ l3) * 8)];
    }
    #pragma unroll
    for (int si = 0; si < 4; ++si)
      #pragma unroll
      for (int sj = 0; sj < 4; ++sj)
        acc[si][sj] = __builtin_amdgcn_mfma_f32_16x16x32_bf16(af[si], bfr[sj], acc[si][sj], 0, 0, 0);
  }

  #pragma unroll
  for (int si = 0; si < 4; ++si)
    #pragma unroll
    for (int sj = 0; sj < 4; ++sj)
      #pragma unroll
      for (int e = 0; e < 4; ++e) {
        int m = m0 + wm * 64 + si * 16 + q * 4 + e;
        int n = n0 + wn * 64 + sj * 16 + l15;
        Cf[(size_t)m * N + n] = acc[si][sj][e] + (bias ? bias[n] : 0.f);
      }
}

// ---------------- fused 2-layer pipelined GRU ----------------
// Grid 256 x 128 thr (1 wg/CU, capacity-safe). Payload identical to r9
// (pack4 u64 publishes, L1 single-read of h0 with a1g fusion). This round:
// NO aggregator -- consumer waves poll the 128 producer slots of their
// domains DIRECTLY (lanes 0-31: own domain, 4 slots/lane dwordx4; lanes
// 32-63: other-layer same-wave domain). Removes 2 MALL hops (aggregator
// notice + flag publish) from every interval's critical chain. seq1's cached
// stores are deferred to after the slot post (out of the producer drain).
// Domains: d = (Lyr1<<1)|w, 128 waves each; epochs monotone; targets
// audited (r7/r8): own >= p+1; other >= p+1 if L1-ph0 else >= p (WAR lag
// guard on h0buf).
__global__ __launch_bounds__(128, 1) void gru_pipe(
    const u16* __restrict__ Wh0, const u16* __restrict__ Wx0,
    const u16* __restrict__ Wh1, const u16* __restrict__ Wx1,
    const float* __restrict__ bz0, const float* __restrict__ br0, const float* __restrict__ bg0,
    const float* __restrict__ bz1, const float* __restrict__ br1, const float* __restrict__ bg1,
    const u16* __restrict__ xb,                      // [32][512][128] bf16
    const float* __restrict__ h0p,                   // (32,2,1024) fp32
    u16* __restrict__ h0buf,                         // 2 x [32][1024] bf16 rotating
    u16* __restrict__ hb1,                           // [32][1024]
    u16* __restrict__ rh0b, u16* __restrict__ rh1b,  // [32][1024]
    u16* __restrict__ seq1,                          // [32][512][1024] bf16
    float* __restrict__ hid,                         // (32,2,1024) fp32 out
    u32* __restrict__ slots)                         // [4][128] wave slots
{
  __shared__ u16 zr_frag[64 * 512];                  // 64 KB max (L1)
  __shared__ u16 g_frag[64 * 256];                   // 32 KB max

  const int tid = threadIdx.x;
  const int lane = tid & 63;
  const int w = tid >> 6;                            // worker wave 0/1
  const int bid = blockIdx.x;

  const bool Lyr1 = bid >= 128;
  const int nb = (bid & 127) * 8;
  const int q = lane >> 4, c15 = lane & 15, nl = c15 & 7;
  const int n_own = nb + nl;
  const bool isz = c15 < 8;
  const int brow = w * 16 + c15;                     // A-fragment batch row
  const int boff = (q * 8 + nl) * 8;                 // g_frag B-fragment offset
  const int aoff = brow * 1024 + q * 8;              // A-fragment element offset
  const int KS = Lyr1 ? 64 : 36;                     // K-steps of 32
  const int IN = Lyr1 ? 1024 : 128;
  const u16* Wh = Lyr1 ? Wh1 : Wh0;
  const u16* Wx = Lyr1 ? Wx1 : Wx0;
  const size_t WXG = (size_t)1024 * IN;              // Wx per-gate elems

  const int d_own = (Lyr1 ? 2 : 0) | w;
  const int d_oth = (Lyr1 ? 0 : 2) | w;
  u32* slot_ptr = &slots[d_own * 128 + (bid & 127)];
  const int othHalf = lane >> 5;                     // 0: poll own, 1: poll other
  const u32* pollp = &slots[(othHalf ? d_oth : d_own) * 128 + (lane & 31) * 4];

  float hreg[4], zreg[4] = {0.f, 0.f, 0.f, 0.f};
  f32x4 a1g = {0.f, 0.f, 0.f, 0.f};                  // L1: g x-side carried ph0->ph1
  u64 p4s[4];                                        // L1: deferred seq1 payload

  // ---- stage concat [Wh | Wx] weights into LDS in MFMA B-frag order ----
  for (int cidx = tid; cidx < KS * 64; cidx += 128) {
    int ks = cidx >> 6, l = cidx & 63;
    int lq = l >> 4, lc = l & 15;
    int row = nb + (lc & 7), gate = (lc < 8) ? 0 : 1;  // z | r
    int k0 = ks * 32 + lq * 8;
    const u16* src = (k0 < 1024)
        ? Wh + (size_t)gate * 1048576 + (size_t)row * 1024 + k0
        : Wx + (size_t)gate * WXG + (size_t)row * IN + (k0 - 1024);
    *(uint4*)&zr_frag[cidx * 8] = *(const uint4*)src;
  }
  for (int gidx = tid; gidx < KS * 32; gidx += 128) {
    int ks = gidx >> 5, s = gidx & 31;
    int lq = s >> 3, r8 = s & 7;
    int row = nb + r8, k0 = ks * 32 + lq * 8;
    const u16* src = (k0 < 1024)
        ? Wh + (size_t)2 * 1048576 + (size_t)row * 1024 + k0
        : Wx + (size_t)2 * WXG + (size_t)row * IN + (k0 - 1024);
    *(uint4*)&g_frag[gidx * 8] = *(const uint4*)src;
  }
  // ---- init state: z-lanes hold h fp32; publish bf16 ----
  #pragma unroll
  for (int e = 0; e < 4; ++e) {
    int b = w * 16 + q * 4 + e;
    float v = h0p[b * 2048 + (Lyr1 ? 1024 : 0) + n_own];
    hreg[e] = v;
    if (isz)
      st_b16_llc((Lyr1 ? hb1 : h0buf + 32768) + b * 1024 + n_own, f2b(v));
  }
  __syncthreads();                                   // drains both waves' vmcnt
  if (lane == 0) st_u32_cc(slot_ptr, 1u);            // post init epoch per wave

  // ---- biases ----
  const float bias1 = isz ? (Lyr1 ? bz1 : bz0)[n_own] : (Lyr1 ? br1 : br0)[n_own];
  const float bias2 = (Lyr1 ? bg1 : bg0)[n_own];

  FU xfu[4];                                         // L0: x frags, live both phases
  FU sA[8], sB[8], sC[8];                            // rotating stream groups (96 VGPR)

  for (int p = 0; p < 1026; ++p) {
    const int t = p >> 1, ph = p & 1;

    // ---- entry wait: direct poll of producer slots (no aggregator hops) ----
    {
      const u32 tgt = othHalf ? ((Lyr1 && ph == 0) ? (u32)(p + 1) : (u32)p)
                              : (u32)(p + 1);
      for (;;) {
        uint4 v = ld_poll4(pollp);
        u32 m = min(min(v.x, v.y), min(v.z, v.w));
        if (__all(m >= tgt)) break;
        __builtin_amdgcn_s_sleep(1);
      }
    }

    if (!Lyr1) {
      if (t < 512) {
        f32x4 a0 = {0.f,0.f,0.f,0.f}, a1 = {0.f,0.f,0.f,0.f};
        if (ph == 0) {
          const u16* hp = h0buf + ((t - 1) & 1) * 32768 + aoff;
          const u16* xp = xb + ((size_t)brow * 512 + t) * 128 + q * 8;
          ISSUE4C(xfu, xp);                          // 4 out
          ISSUE8CC(sA, hp);                          // 12
          ISSUE8CC(sB, hp + 256);                    // 20
          ISSUE8CC(sC, hp + 512);                    // 28
          WAITV(16); MFMA8ZR(a0, sA, 0);             // xfu+sA done
          ISSUE8CC(sA, hp + 768);                    // 24
          WAITV(16); MFMA8ZR(a0, sB, 8);
          WAITV(8);  MFMA8ZR(a0, sC, 16);
          WAITV(0);  MFMA8ZR(a0, sA, 24);
          #pragma unroll
          for (int j = 0; j < 4; ++j)
            a1 = __builtin_amdgcn_mfma_f32_16x16x32_bf16(
                xfu[j].h, *(const bf16x8*)&zr_frag[(32 + j) * 512 + lane * 8], a1, 0, 0, 0);
          float hsh[4];
          #pragma unroll
          for (int e = 0; e < 4; ++e) hsh[e] = __shfl_xor(hreg[e], 8);
          #pragma unroll
          for (int e = 0; e < 4; ++e) {
            float pre = a0[e] + a1[e] + bias1;
            float s = 1.f / (1.f + __expf(-pre));
            if (isz) zreg[e] = s;
            else {
              u64 p4 = pack4((u32)f2b(s * hsh[e]));
              if ((c15 & 3) == 0)
                st_u64_cc(&rh0b[(w * 16 + q * 4 + e) * 1024 + nb + (c15 & 7)], p4);
            }
          }
        } else {
          const u16* rp = rh0b + aoff;
          ISSUE8CC(sA, rp);                          // 8
          ISSUE8CC(sB, rp + 256);                    // 16
          ISSUE8CC(sC, rp + 512);                    // 24
          WAITV(16); MFMA8G(a0, sA, 0);
          ISSUE8CC(sA, rp + 768);                    // 24
          WAITV(16); MFMA8G(a0, sB, 8);
          WAITV(8);  MFMA8G(a0, sC, 16);
          WAITV(0);  MFMA8G(a0, sA, 24);
          #pragma unroll
          for (int j = 0; j < 4; ++j)
            a1 = __builtin_amdgcn_mfma_f32_16x16x32_bf16(
                xfu[j].h, *(const bf16x8*)&g_frag[(32 + j) * 256 + boff], a1, 0, 0, 0);
          if (isz) {
            u16* hout = h0buf + (t & 1) * 32768;
            #pragma unroll
            for (int e = 0; e < 4; ++e) {
              int b = w * 16 + q * 4 + e;
              float pre = a0[e] + a1[e] + bias2;
              float ex = __expf(2.f * pre);
              float gv = 1.f - 2.f / (ex + 1.f);      // tanh, overflow-safe
              float hn = zreg[e] * hreg[e] + (1.f - zreg[e]) * gv;
              hreg[e] = hn;
              u64 p4 = pack4((u32)f2b(hn));
              if ((c15 & 3) == 0) st_u64_cc(&hout[b * 1024 + nb + c15], p4);
              if (t == 511) hid[b * 2048 + n_own] = hn;
            }
          }
        }
      }
    } else {
      if (t >= 1) {
        const int s = t - 1;
        f32x4 a0 = {0.f,0.f,0.f,0.f}, a1 = {0.f,0.f,0.f,0.f};
        if (ph == 0) {
          const u16* hp = h0buf + (s & 1) * 32768 + aoff;
          const u16* hb = hb1 + aoff;
          a1g = (f32x4){0.f, 0.f, 0.f, 0.f};
          ISSUE8CC(sA, hb);                          // 8
          ISSUE8CC(sB, hb + 256);                    // 16
          ISSUE8CC(sC, hb + 512);                    // 24
          WAITV(16); MFMA8ZR(a0, sA, 0);  ISSUE8CC(sA, hb + 768);   // 24
          WAITV(16); MFMA8ZR(a0, sB, 8);  ISSUE8CC(sB, hp);         // 24
          WAITV(16); MFMA8ZR(a0, sC, 16); ISSUE8CC(sC, hp + 256);   // 24
          WAITV(16); MFMA8ZR(a0, sA, 24); ISSUE8CC(sA, hp + 512);   // 24
          WAITV(16); MFMA8ZR(a1, sB, 32); MFMA8G(a1g, sB, 32);
                     ISSUE8CC(sB, hp + 768);                        // 24
          WAITV(16); MFMA8ZR(a1, sC, 40); MFMA8G(a1g, sC, 40);
          WAITV(8);  MFMA8ZR(a1, sA, 48); MFMA8G(a1g, sA, 48);
          WAITV(0);  MFMA8ZR(a1, sB, 56); MFMA8G(a1g, sB, 56);
          float hsh[4];
          #pragma unroll
          for (int e = 0; e < 4; ++e) hsh[e] = __shfl_xor(hreg[e], 8);
          #pragma unroll
          for (int e = 0; e < 4; ++e) {
            float pre = a0[e] + a1[e] + bias1;
            float sg = 1.f / (1.f + __expf(-pre));
            if (isz) zreg[e] = sg;
            else {
              u64 p4 = pack4((u32)f2b(sg * hsh[e]));
              if ((c15 & 3) == 0)
                st_u64_cc(&rh1b[(w * 16 + q * 4 + e) * 1024 + nb + (c15 & 7)], p4);
            }
          }
        } else {
          const u16* rp = rh1b + aoff;
          ISSUE8CC(sA, rp);                          // 8
          ISSUE8CC(sB, rp + 256);                    // 16
          ISSUE8CC(sC, rp + 512);                    // 24
          WAITV(16); MFMA8G(a0, sA, 0);
          ISSUE8CC(sA, rp + 768);                    // 24
          WAITV(16); MFMA8G(a0, sB, 8);
          WAITV(8);  MFMA8G(a0, sC, 16);
          WAITV(0);  MFMA8G(a0, sA, 24);
          if (isz) {
            #pragma unroll
            for (int e = 0; e < 4; ++e) {
              int b = w * 16 + q * 4 + e;
              float pre = a0[e] + a1g[e] + bias2;     // x-side pre-accumulated in ph0
              float ex = __expf(2.f * pre);
              float gv = 1.f - 2.f / (ex + 1.f);
              float hn = zreg[e] * hreg[e] + (1.f - zreg[e]) * gv;
              hreg[e] = hn;
              u64 p4 = pack4((u32)f2b(hn));
              p4s[e] = p4;                            // seq1 deferred past slot post
              if ((c15 & 3) == 0) st_u64_cc(&hb1[b * 1024 + nb + c15], p4);
              if (s == 511) hid[1024 + b * 2048 + n_own] = hn;
            }
          }
        }
      }
    }

    // ---- per-wave arrival (last interval posts nothing) ----
    if (p < 1025) {
      WAITV(0);                                      // drain this wave's sc stores
      if (lane == 0) st_u32_cc(slot_ptr, (u32)(p + 2));
    }
    // ---- deferred seq1 writes (cached; off the producer drain path) ----
    if (Lyr1 && ph == 1 && t >= 1 && isz && (c15 & 3) == 0) {
      #pragma unroll
      for (int e = 0; e < 4; ++e)
        *(u64*)&seq1[((size_t)(w * 16 + q * 4 + e) * 512 + (t - 1)) * 1024 + nb + c15] = p4s[e];
    }
  }
}

// ---------------- host ----------------
extern "C" void kernel_launch(void* const* d_in, const int* in_sizes, int n_in,
                              void* d_out, int out_size, void* d_ws, size_t ws_size,
                              hipStream_t stream) {
  (void)in_sizes; (void)n_in; (void)out_size; (void)ws_size;
  char* ws = (char*)d_ws;
  const size_t MB = 1024ull * 1024ull;
  u16* seq1 = (u16*)(ws + 0);                         // 32 MB
  u16* xb   = (u16*)(ws + 32 * MB);                   // 4 MB
  u16* Wh0  = (u16*)(ws + 36 * MB);                   // 6 MB
  u16* Wh1  = (u16*)(ws + 42 * MB);                   // 6 MB
  u16* Wx0  = (u16*)(ws + 48 * MB);                   // 0.75 MB
  u16* Wx1  = (u16*)(ws + 49 * MB);                   // 6 MB
  u16* Wyb  = (u16*)(ws + 55 * MB);                   // 0.25 MB
  u16* h0buf = (u16*)(ws + 56 * MB);                  // 2 x 64 KB
  u16* hb1  = (u16*)(ws + 56 * MB + 128 * 1024);      // 64 KB
  u16* rh0b = (u16*)(ws + 56 * MB + 192 * 1024);      // 64 KB
  u16* rh1b = (u16*)(ws + 56 * MB + 256 * 1024);      // 64 KB
  u32* slots = (u32*)(ws + 56 * MB + 320 * 1024);     // [4][128] = 2 KB

  hipMemsetAsync(slots, 0, 4096, stream);

  auto cast = [&](const void* in, u16* out, int n) {
    cast_f32_bf16<<<(n + 255) / 256, 256, 0, stream>>>((const float*)in, out, n);
  };
  cast(d_in[0], xb, 2097152);                               // x
  cast(d_in[3],  Wh0 + 0,       1048576);                   // Whz0
  cast(d_in[6],  Wh0 + 1048576, 1048576);                   // Whr0
  cast(d_in[9],  Wh0 + 2097152, 1048576);                   // Whg0
  cast(d_in[12], Wh1 + 0,       1048576);                   // Whz1
  cast(d_in[15], Wh1 + 1048576, 1048576);                   // Whr1
  cast(d_in[18], Wh1 + 2097152, 1048576);                   // Whg1
  cast(d_in[2],  Wx0 + 0,      131072);                     // Wxz0
  cast(d_in[5],  Wx0 + 131072, 131072);                     // Wxr0
  cast(d_in[8],  Wx0 + 262144, 131072);                     // Wxg0
  cast(d_in[11], Wx1 + 0,       1048576);                   // Wxz1
  cast(d_in[14], Wx1 + 1048576, 1048576);                   // Wxr1
  cast(d_in[17], Wx1 + 2097152, 1048576);                   // Wxg1
  cast(d_in[20], Wyb, 131072);                              // Wy

  float* y_out = (float*)d_out;
  float* hid = y_out + 2097152;                             // hidden (32,2,1024)

  gru_pipe<<<256, dim3(128), 0, stream>>>(
      Wh0, Wx0, Wh1, Wx1,
      (const float*)d_in[4],  (const float*)d_in[7],  (const float*)d_in[10],
      (const float*)d_in[13], (const float*)d_in[16], (const float*)d_in[19],
      xb, (const float*)d_in[1],
      h0buf, hb1, rh0b, rh1b, seq1, hid, slots);

  // output projection y = seq1 @ Wy^T + by  (M=16384, N=128, K=1024)
  gemm_bt<<<dim3(128, 1), dim3(256), 0, stream>>>(
      seq1, Wyb, 16384, 128, 1024, (const float*)d_in[21], y_out);
}

// Round 11
// 6282.704 us; speedup vs baseline: 1.4401x; 1.4401x over previous
//
#include <hip/hip_runtime.h>

typedef unsigned short u16;
typedef unsigned int u32;
typedef unsigned long long u64;
typedef __bf16 bf16x8 __attribute__((ext_vector_type(8)));
typedef float f32x4 __attribute__((ext_vector_type(4)));

union FU { f32x4 f; bf16x8 h; };

__device__ __forceinline__ u16 f2b(float f) {
  unsigned u = __float_as_uint(f);
  return (u16)((u + 0x7fffu + ((u >> 16) & 1u)) >> 16);
}

// per-lane coherent 2B store (init only; cold path)
__device__ __forceinline__ void st_b16_llc(u16* p, u16 v) {
  __hip_atomic_store(p, v, __ATOMIC_RELAXED, __HIP_MEMORY_SCOPE_AGENT);
}

// plain coherent stores (wave-coalesced; no TCC atomic serialization)
__device__ __forceinline__ void st_u32_cc(u32* p, u32 v) {
  asm volatile("global_store_dword %0, %1, off sc0 sc1" :: "v"(p), "v"(v) : "memory");
}
__device__ __forceinline__ void st_u64_cc(void* p, u64 v) {
  asm volatile("global_store_dwordx2 %0, %1, off sc0 sc1" :: "v"(p), "v"(v) : "memory");
}

// coherent dword load (poll path; valid on return)
__device__ __forceinline__ u32 ld_dword_cc(const u32* p) {
  u32 v;
  asm volatile("global_load_dword %0, %1, off sc0 sc1\n\ts_waitcnt vmcnt(0)"
               : "=v"(v) : "v"(p) : "memory");
  return v;
}

// pack 4 neighboring lanes' bf16 into one u64 (lanes c15&3==0 hold cols +0..3)
// partners (xor 1, xor 2) stay inside the active 8-lane publish group.
__device__ __forceinline__ u64 pack4(u32 lo) {
  u32 p2 = lo | ((u32)__shfl_xor((int)lo, 1) << 16);
  return (u64)p2 | ((u64)(u32)__shfl_xor((int)p2, 2) << 32);
}

// issue 8 coherent 16B loads (covers 8 k-steps = 256 u16); valid after WAITV
#define ISSUE8CC(D, P)                                                       \
  asm volatile(                                                              \
      "global_load_dwordx4 %0, %8, off sc0 sc1\n\t"                          \
      "global_load_dwordx4 %1, %8, off offset:64 sc0 sc1\n\t"                \
      "global_load_dwordx4 %2, %8, off offset:128 sc0 sc1\n\t"               \
      "global_load_dwordx4 %3, %8, off offset:192 sc0 sc1\n\t"               \
      "global_load_dwordx4 %4, %8, off offset:256 sc0 sc1\n\t"               \
      "global_load_dwordx4 %5, %8, off offset:320 sc0 sc1\n\t"               \
      "global_load_dwordx4 %6, %8, off offset:384 sc0 sc1\n\t"               \
      "global_load_dwordx4 %7, %8, off offset:448 sc0 sc1"                   \
      : "=&v"((D)[0].f), "=&v"((D)[1].f), "=&v"((D)[2].f), "=&v"((D)[3].f),  \
        "=&v"((D)[4].f), "=&v"((D)[5].f), "=&v"((D)[6].f), "=&v"((D)[7].f)   \
      : "v"(P) : "memory")

// issue 4 cached 16B loads (read-only x data; counted in vmcnt like the rest)
#define ISSUE4C(D, P)                                                        \
  asm volatile(                                                              \
      "global_load_dwordx4 %0, %4, off\n\t"                                  \
      "global_load_dwordx4 %1, %4, off offset:64\n\t"                        \
      "global_load_dwordx4 %2, %4, off offset:128\n\t"                       \
      "global_load_dwordx4 %3, %4, off offset:192"                           \
      : "=&v"((D)[0].f), "=&v"((D)[1].f), "=&v"((D)[2].f), "=&v"((D)[3].f)   \
      : "v"(P) : "memory")

// counted wait + hard scheduling fence (rule #18: consumers stay below)
#define WAITV(N)                                                             \
  do {                                                                       \
    asm volatile("s_waitcnt vmcnt(" #N ")" ::: "memory");                    \
    __builtin_amdgcn_sched_barrier(0);                                       \
  } while (0)

// 8 MFMAs: A-frags from BUF, B-frags from LDS (zr layout / g layout)
#define MFMA8ZR(ACC, BUF, KSB)                                               \
  do {                                                                       \
    _Pragma("unroll") for (int j_ = 0; j_ < 8; ++j_)                         \
        ACC = __builtin_amdgcn_mfma_f32_16x16x32_bf16(                       \
            (BUF)[j_].h,                                                     \
            *(const bf16x8*)&zr_frag[(KSB + j_) * 512 + lane * 8],           \
            ACC, 0, 0, 0);                                                   \
  } while (0)
#define MFMA8G(ACC, BUF, KSB)                                                \
  do {                                                                       \
    _Pragma("unroll") for (int j_ = 0; j_ < 8; ++j_)                         \
        ACC = __builtin_amdgcn_mfma_f32_16x16x32_bf16(                       \
            (BUF)[j_].h,                                                     \
            *(const bf16x8*)&g_frag[(KSB + j_) * 256 + boff],                \
            ACC, 0, 0, 0);                                                   \
  } while (0)

// ---------------- generic fp32 -> bf16 cast ----------------
__global__ void cast_f32_bf16(const float* __restrict__ in, u16* __restrict__ out, int n) {
  int i = blockIdx.x * 256 + threadIdx.x;
  if (i < n) out[i] = f2b(in[i]);
}

// ---------------- tiled bf16 GEMM: C[M,N] = A[M,K] @ B[N,K]^T (fp32 out) ----------------
__global__ __launch_bounds__(256) void gemm_bt(
    const u16* __restrict__ A, const u16* __restrict__ B,
    int M, int N, int K,
    const float* __restrict__ bias, float* __restrict__ Cf)
{
  __shared__ u16 a_sm[128 * 32];
  __shared__ u16 b_sm[128 * 32];
  const int tid = threadIdx.x;
  const int lane = tid & 63;
  const int wid = tid >> 6;
  const int wm = wid >> 1, wn = wid & 1;
  const int m0 = blockIdx.x * 128, n0 = blockIdx.y * 128;
  const int q = lane >> 4, l15 = lane & 15, l3 = lane & 3;

  f32x4 acc[4][4];
  #pragma unroll
  for (int i = 0; i < 4; ++i)
    #pragma unroll
    for (int j = 0; j < 4; ++j) acc[i][j] = (f32x4){0.f, 0.f, 0.f, 0.f};

  for (int kk = 0; kk < K; kk += 32) {
    __syncthreads();
    #pragma unroll
    for (int p = 0; p < 2; ++p) {
      int idx = p * 256 + tid;
      int r = idx >> 2, cch = idx & 3;
      *(uint4*)&a_sm[r * 32 + ((cch ^ (r & 3)) * 8)] =
          *(const uint4*)&A[(size_t)(m0 + r) * K + kk + cch * 8];
      *(uint4*)&b_sm[r * 32 + ((cch ^ (r & 3)) * 8)] =
          *(const uint4*)&B[(size_t)(n0 + r) * K + kk + cch * 8];
    }
    __syncthreads();
    bf16x8 af[4], bfr[4];
    #pragma unroll
    for (int s = 0; s < 4; ++s) {
      int ra = wm * 64 + s * 16 + l15;
      af[s] = *(const bf16x8*)&a_sm[ra * 32 + ((q ^ l3) * 8)];
      int rb = wn * 64 + s * 16 + l15;
      bfr[s] = *(const bf16x8*)&b_sm[rb * 32 + ((q ^ l3) * 8)];
    }
    #pragma unroll
    for (int si = 0; si < 4; ++si)
      #pragma unroll
      for (int sj = 0; sj < 4; ++sj)
        acc[si][sj] = __builtin_amdgcn_mfma_f32_16x16x32_bf16(af[si], bfr[sj], acc[si][sj], 0, 0, 0);
  }

  #pragma unroll
  for (int si = 0; si < 4; ++si)
    #pragma unroll
    for (int sj = 0; sj < 4; ++sj)
      #pragma unroll
      for (int e = 0; e < 4; ++e) {
        int m = m0 + wm * 64 + si * 16 + q * 4 + e;
        int n = n0 + wn * 64 + sj * 16 + l15;
        Cf[(size_t)m * N + n] = acc[si][sj][e] + (bias ? bias[n] : 0.f);
      }
}

// ---------------- fused 2-layer pipelined GRU ----------------
// r9 structure (best, 5.95ms): grid 256 x 192 thr, waves 0-1 work, wave 2 of
// bid 0 aggregates 4 per-(layer x wave) domains into replicated flag lines.
// Round-11 deltas:
//  (1) h0buf 4-deep: L0's WAR lag guard relaxes oth>=p to oth>=p-4, so L0
//      free-runs ahead and L1's oth>=p+1 wait is always-satisfied -- the
//      interval rate decouples from max(L0,L1) straggler spread to L1-only.
//      (Safe since r8's a1g fusion: L1 reads h0buf in ph0 ONLY; buffer
//      (t-4)&3 is read-complete at interval 2t-6, posted 2t-4 >= p-5.)
//  (2) L1 ph1 cross-layer wait dropped (reads only rh1b post-fusion).
//  (3) 16 replica flag lines (was 8), published by ONE parallel per-lane
//      store (lane -> replica lane&15, domain lane>>4): halves consumer
//      waves/line (64->32) and removes serial publish -- r10 proved hot-line
//      request pressure is the dominant sync cost.
__global__ __launch_bounds__(192, 1) void gru_pipe(
    const u16* __restrict__ Wh0, const u16* __restrict__ Wx0,
    const u16* __restrict__ Wh1, const u16* __restrict__ Wx1,
    const float* __restrict__ bz0, const float* __restrict__ br0, const float* __restrict__ bg0,
    const float* __restrict__ bz1, const float* __restrict__ br1, const float* __restrict__ bg1,
    const u16* __restrict__ xb,                      // [32][512][128] bf16
    const float* __restrict__ h0p,                   // (32,2,1024) fp32
    u16* __restrict__ h0buf,                         // 4 x [32][1024] bf16 rotating
    u16* __restrict__ hb1,                           // [32][1024]
    u16* __restrict__ rh0b, u16* __restrict__ rh1b,  // [32][1024]
    u16* __restrict__ seq1,                          // [32][512][1024] bf16
    float* __restrict__ hid,                         // (32,2,1024) fp32 out
    u32* __restrict__ slots)                         // 512 slots + 16x32 lflags
{
  __shared__ u16 zr_frag[64 * 512];                  // 64 KB max (L1)
  __shared__ u16 g_frag[64 * 256];                   // 32 KB max

  const int tid = threadIdx.x;
  const int lane = tid & 63;
  const int w = tid >> 6;                            // 0,1 = worker; 2 = agg/idle
  const int bid = blockIdx.x;
  u32* lflags = slots + 512;

  const bool Lyr1 = bid >= 128;
  const int nb = (bid & 127) * 8;
  const int q = lane >> 4, c15 = lane & 15, nl = c15 & 7;
  const int n_own = nb + nl;
  const bool isz = c15 < 8;
  const int brow = w * 16 + c15;                     // A-fragment batch row
  const int boff = (q * 8 + nl) * 8;                 // g_frag B-fragment offset
  const int aoff = brow * 1024 + q * 8;              // A-fragment element offset
  const int KS = Lyr1 ? 64 : 36;                     // K-steps of 32
  const int IN = Lyr1 ? 1024 : 128;
  const u16* Wh = Lyr1 ? Wh1 : Wh0;
  const u16* Wx = Lyr1 ? Wx1 : Wx0;
  const size_t WXG = (size_t)1024 * IN;              // Wx per-gate elems

  const int d_own = (Lyr1 ? 2 : 0) | (w & 1);
  const int d_oth = (Lyr1 ? 0 : 2) | (w & 1);
  u32* slot_ptr = &slots[d_own * 128 + (bid & 127)];
  const int rrep = (bid >> 4) & 15;                  // replica line 0..15
  const bool laneOth = (lane & 1) != 0;
  const u32* lfp = &lflags[rrep * 32 + (laneOth ? d_oth : d_own)];

  float hreg[4], zreg[4] = {0.f, 0.f, 0.f, 0.f};
  f32x4 a1g = {0.f, 0.f, 0.f, 0.f};                  // L1: g x-side carried ph0->ph1

  if (tid < 128) {
    // ---- stage concat [Wh | Wx] weights into LDS in MFMA B-frag order ----
    for (int cidx = tid; cidx < KS * 64; cidx += 128) {
      int ks = cidx >> 6, l = cidx & 63;
      int lq = l >> 4, lc = l & 15;
      int row = nb + (lc & 7), gate = (lc < 8) ? 0 : 1;  // z | r
      int k0 = ks * 32 + lq * 8;
      const u16* src = (k0 < 1024)
          ? Wh + (size_t)gate * 1048576 + (size_t)row * 1024 + k0
          : Wx + (size_t)gate * WXG + (size_t)row * IN + (k0 - 1024);
      *(uint4*)&zr_frag[cidx * 8] = *(const uint4*)src;
    }
    for (int gidx = tid; gidx < KS * 32; gidx += 128) {
      int ks = gidx >> 5, s = gidx & 31;
      int lq = s >> 3, r8 = s & 7;
      int row = nb + r8, k0 = ks * 32 + lq * 8;
      const u16* src = (k0 < 1024)
          ? Wh + (size_t)2 * 1048576 + (size_t)row * 1024 + k0
          : Wx + (size_t)2 * WXG + (size_t)row * IN + (k0 - 1024);
      *(uint4*)&g_frag[gidx * 8] = *(const uint4*)src;
    }
    // ---- init state: z-lanes hold h fp32; publish bf16 ----
    // L0's initial h goes to buffer (t-1)&3 for t=0 -> index 3.
    #pragma unroll
    for (int e = 0; e < 4; ++e) {
      int b = w * 16 + q * 4 + e;
      float v = h0p[b * 2048 + (Lyr1 ? 1024 : 0) + n_own];
      hreg[e] = v;
      if (isz)
        st_b16_llc((Lyr1 ? hb1 : h0buf + 3 * 32768) + b * 1024 + n_own, f2b(v));
    }
  }
  __syncthreads();                                   // all 3 waves; drains vmcnt

  // ---------- aggregator / idle third wave ----------
  if (w == 2) {
    if (bid == 0) {
      const u32* my = slots + lane * 8;              // 8 slots per lane = 512
      const int dgrp = lane >> 4;                    // domain this lane reduces
      u32* myflag = &lflags[(lane & 15) * 32 + dgrp]; // parallel publish cell
      u32 pub = 0;
      for (;;) {
        uint4 va, vb;
        asm volatile(
            "global_load_dwordx4 %0, %2, off sc0 sc1\n\t"
            "global_load_dwordx4 %1, %2, off offset:16 sc0 sc1\n\t"
            "s_waitcnt vmcnt(0)"
            : "=&v"(va), "=&v"(vb) : "v"(my) : "memory");
        u32 m = min(min(min(va.x, va.y), min(va.z, va.w)),
                    min(min(vb.x, vb.y), min(vb.z, vb.w)));
        m = min(m, (u32)__shfl_xor((int)m, 1));
        m = min(m, (u32)__shfl_xor((int)m, 2));
        m = min(m, (u32)__shfl_xor((int)m, 4));
        m = min(m, (u32)__shfl_xor((int)m, 8));
        if (m > pub) { pub = m; st_u32_cc(myflag, m); }
        if (__all(pub >= 1026u)) break;
        __builtin_amdgcn_s_sleep(1);
      }
    }
    return;
  }

  // post init arrival (epoch 1) per wave
  if (lane == 0) st_u32_cc(slot_ptr, 1u);

  // ---- biases ----
  const float bias1 = isz ? (Lyr1 ? bz1 : bz0)[n_own] : (Lyr1 ? br1 : br0)[n_own];
  const float bias2 = (Lyr1 ? bg1 : bg0)[n_own];

  FU xfu[4];                                         // L0: x frags, live both phases
  FU sA[8], sB[8], sC[8];                            // rotating stream groups (96 VGPR)

  for (int p = 0; p < 1026; ++p) {
    const int t = p >> 1, ph = p & 1;

    // ---- entry wait (both waves poll; no intra-wg barriers in the loop) ----
    {
      u32 tgt;
      if (!laneOth) tgt = (u32)(p + 1);              // own domain: fresh
      else if (!Lyr1) tgt = (p > 4) ? (u32)(p - 4) : 0u;  // WAR lag guard, 4-deep
      else tgt = (ph == 0) ? (u32)(p + 1) : 0u;      // L1 ph1: no cross dep
      for (;;) {
        u32 v = ld_dword_cc(lfp);
        if (__all(v >= tgt)) break;
        __builtin_amdgcn_s_sleep(1);
      }
    }

    if (!Lyr1) {
      if (t < 512) {
        f32x4 a0 = {0.f,0.f,0.f,0.f}, a1 = {0.f,0.f,0.f,0.f};
        if (ph == 0) {
          const u16* hp = h0buf + ((t - 1) & 3) * 32768 + aoff;
          const u16* xp = xb + ((size_t)brow * 512 + t) * 128 + q * 8;
          ISSUE4C(xfu, xp);                          // 4 out
          ISSUE8CC(sA, hp);                          // 12
          ISSUE8CC(sB, hp + 256);                    // 20
          ISSUE8CC(sC, hp + 512);                    // 28
          WAITV(16); MFMA8ZR(a0, sA, 0);             // xfu+sA done
          ISSUE8CC(sA, hp + 768);                    // 24
          WAITV(16); MFMA8ZR(a0, sB, 8);
          WAITV(8);  MFMA8ZR(a0, sC, 16);
          WAITV(0);  MFMA8ZR(a0, sA, 24);
          #pragma unroll
          for (int j = 0; j < 4; ++j)
            a1 = __builtin_amdgcn_mfma_f32_16x16x32_bf16(
                xfu[j].h, *(const bf16x8*)&zr_frag[(32 + j) * 512 + lane * 8], a1, 0, 0, 0);
          float hsh[4];
          #pragma unroll
          for (int e = 0; e < 4; ++e) hsh[e] = __shfl_xor(hreg[e], 8);
          #pragma unroll
          for (int e = 0; e < 4; ++e) {
            float pre = a0[e] + a1[e] + bias1;
            float s = 1.f / (1.f + __expf(-pre));
            if (isz) zreg[e] = s;
            else {
              u64 p4 = pack4((u32)f2b(s * hsh[e]));
              if ((c15 & 3) == 0)
                st_u64_cc(&rh0b[(w * 16 + q * 4 + e) * 1024 + nb + (c15 & 7)], p4);
            }
          }
        } else {
          const u16* rp = rh0b + aoff;
          ISSUE8CC(sA, rp);                          // 8
          ISSUE8CC(sB, rp + 256);                    // 16
          ISSUE8CC(sC, rp + 512);                    // 24
          WAITV(16); MFMA8G(a0, sA, 0);
          ISSUE8CC(sA, rp + 768);                    // 24
          WAITV(16); MFMA8G(a0, sB, 8);
          WAITV(8);  MFMA8G(a0, sC, 16);
          WAITV(0);  MFMA8G(a0, sA, 24);
          #pragma unroll
          for (int j = 0; j < 4; ++j)
            a1 = __builtin_amdgcn_mfma_f32_16x16x32_bf16(
                xfu[j].h, *(const bf16x8*)&g_frag[(32 + j) * 256 + boff], a1, 0, 0, 0);
          if (isz) {
            u16* hout = h0buf + (t & 3) * 32768;
            #pragma unroll
            for (int e = 0; e < 4; ++e) {
              int b = w * 16 + q * 4 + e;
              float pre = a0[e] + a1[e] + bias2;
              float ex = __expf(2.f * pre);
              float gv = 1.f - 2.f / (ex + 1.f);      // tanh, overflow-safe
              float hn = zreg[e] * hreg[e] + (1.f - zreg[e]) * gv;
              hreg[e] = hn;
              u64 p4 = pack4((u32)f2b(hn));
              if ((c15 & 3) == 0) st_u64_cc(&hout[b * 1024 + nb + c15], p4);
              if (t == 511) hid[b * 2048 + n_own] = hn;
            }
          }
        }
      }
    } else {
      if (t >= 1) {
        const int s = t - 1;
        f32x4 a0 = {0.f,0.f,0.f,0.f}, a1 = {0.f,0.f,0.f,0.f};
        if (ph == 0) {
          const u16* hp = h0buf + (s & 3) * 32768 + aoff;
          const u16* hb = hb1 + aoff;
          a1g = (f32x4){0.f, 0.f, 0.f, 0.f};
          ISSUE8CC(sA, hb);                          // 8
          ISSUE8CC(sB, hb + 256);                    // 16
          ISSUE8CC(sC, hb + 512);                    // 24
          WAITV(16); MFMA8ZR(a0, sA, 0);  ISSUE8CC(sA, hb + 768);   // 24
          WAITV(16); MFMA8ZR(a0, sB, 8);  ISSUE8CC(sB, hp);         // 24
          WAITV(16); MFMA8ZR(a0, sC, 16); ISSUE8CC(sC, hp + 256);   // 24
          WAITV(16); MFMA8ZR(a0, sA, 24); ISSUE8CC(sA, hp + 512);   // 24
          WAITV(16); MFMA8ZR(a1, sB, 32); MFMA8G(a1g, sB, 32);
                     ISSUE8CC(sB, hp + 768);                        // 24
          WAITV(16); MFMA8ZR(a1, sC, 40); MFMA8G(a1g, sC, 40);
          WAITV(8);  MFMA8ZR(a1, sA, 48); MFMA8G(a1g, sA, 48);
          WAITV(0);  MFMA8ZR(a1, sB, 56); MFMA8G(a1g, sB, 56);
          float hsh[4];
          #pragma unroll
          for (int e = 0; e < 4; ++e) hsh[e] = __shfl_xor(hreg[e], 8);
          #pragma unroll
          for (int e = 0; e < 4; ++e) {
            float pre = a0[e] + a1[e] + bias1;
            float sg = 1.f / (1.f + __expf(-pre));
            if (isz) zreg[e] = sg;
            else {
              u64 p4 = pack4((u32)f2b(sg * hsh[e]));
              if ((c15 & 3) == 0)
                st_u64_cc(&rh1b[(w * 16 + q * 4 + e) * 1024 + nb + (c15 & 7)], p4);
            }
          }
        } else {
          const u16* rp = rh1b + aoff;
          ISSUE8CC(sA, rp);                          // 8
          ISSUE8CC(sB, rp + 256);                    // 16
          ISSUE8CC(sC, rp + 512);                    // 24
          WAITV(16); MFMA8G(a0, sA, 0);
          ISSUE8CC(sA, rp + 768);                    // 24
          WAITV(16); MFMA8G(a0, sB, 8);
          WAITV(8);  MFMA8G(a0, sC, 16);
          WAITV(0);  MFMA8G(a0, sA, 24);
          if (isz) {
            #pragma unroll
            for (int e = 0; e < 4; ++e) {
              int b = w * 16 + q * 4 + e;
              float pre = a0[e] + a1g[e] + bias2;     // x-side pre-accumulated in ph0
              float ex = __expf(2.f * pre);
              float gv = 1.f - 2.f / (ex + 1.f);
              float hn = zreg[e] * hreg[e] + (1.f - zreg[e]) * gv;
              hreg[e] = hn;
              u64 p4 = pack4((u32)f2b(hn));
              if ((c15 & 3) == 0) {
                st_u64_cc(&hb1[b * 1024 + nb + c15], p4);
                *(u64*)&seq1[((size_t)b * 512 + s) * 1024 + nb + c15] = p4;
              }
              if (s == 511) hid[1024 + b * 2048 + n_own] = hn;
            }
          }
        }
      }
    }

    // ---- per-wave arrival (last interval posts nothing) ----
    if (p < 1025) {
      WAITV(0);                                      // drain this wave's stores
      if (lane == 0) st_u32_cc(slot_ptr, (u32)(p + 2));
    }
  }
}

// ---------------- host ----------------
extern "C" void kernel_launch(void* const* d_in, const int* in_sizes, int n_in,
                              void* d_out, int out_size, void* d_ws, size_t ws_size,
                              hipStream_t stream) {
  (void)in_sizes; (void)n_in; (void)out_size; (void)ws_size;
  char* ws = (char*)d_ws;
  const size_t MB = 1024ull * 1024ull;
  u16* seq1 = (u16*)(ws + 0);                         // 32 MB
  u16* xb   = (u16*)(ws + 32 * MB);                   // 4 MB
  u16* Wh0  = (u16*)(ws + 36 * MB);                   // 6 MB
  u16* Wh1  = (u16*)(ws + 42 * MB);                   // 6 MB
  u16* Wx0  = (u16*)(ws + 48 * MB);                   // 0.75 MB
  u16* Wx1  = (u16*)(ws + 49 * MB);                   // 6 MB
  u16* Wyb  = (u16*)(ws + 55 * MB);                   // 0.25 MB
  u16* h0buf = (u16*)(ws + 56 * MB);                  // 4 x 64 KB rotating
  u16* hb1  = (u16*)(ws + 56 * MB + 256 * 1024);      // 64 KB
  u16* rh0b = (u16*)(ws + 56 * MB + 320 * 1024);      // 64 KB
  u16* rh1b = (u16*)(ws + 56 * MB + 384 * 1024);      // 64 KB
  u32* slots = (u32*)(ws + 56 * MB + 448 * 1024);     // 512 slots + 16x32 lflags

  hipMemsetAsync(slots, 0, 8192, stream);

  auto cast = [&](const void* in, u16* out, int n) {
    cast_f32_bf16<<<(n + 255) / 256, 256, 0, stream>>>((const float*)in, out, n);
  };
  cast(d_in[0], xb, 2097152);                               // x
  cast(d_in[3],  Wh0 + 0,       1048576);                   // Whz0
  cast(d_in[6],  Wh0 + 1048576, 1048576);                   // Whr0
  cast(d_in[9],  Wh0 + 2097152, 1048576);                   // Whg0
  cast(d_in[12], Wh1 + 0,       1048576);                   // Whz1
  cast(d_in[15], Wh1 + 1048576, 1048576);                   // Whr1
  cast(d_in[18], Wh1 + 2097152, 1048576);                   // Whg1
  cast(d_in[2],  Wx0 + 0,      131072);                     // Wxz0
  cast(d_in[5],  Wx0 + 131072, 131072);                     // Wxr0
  cast(d_in[8],  Wx0 + 262144, 131072);                     // Wxg0
  cast(d_in[11], Wx1 + 0,       1048576);                   // Wxz1
  cast(d_in[14], Wx1 + 1048576, 1048576);                   // Wxr1
  cast(d_in[17], Wx1 + 2097152, 1048576);                   // Wxg1
  cast(d_in[20], Wyb, 131072);                              // Wy

  float* y_out = (float*)d_out;
  float* hid = y_out + 2097152;                             // hidden (32,2,1024)

  gru_pipe<<<256, dim3(192), 0, stream>>>(
      Wh0, Wx0, Wh1, Wx1,
      (const float*)d_in[4],  (const float*)d_in[7],  (const float*)d_in[10],
      (const float*)d_in[13], (const float*)d_in[16], (const float*)d_in[19],
      xb, (const float*)d_in[1],
      h0buf, hb1, rh0b, rh1b, seq1, hid, slots);

  // output projection y = seq1 @ Wy^T + by  (M=16384, N=128, K=1024)
  gemm_bt<<<dim3(128, 1), dim3(256), 0, stream>>>(
      seq1, Wyb, 16384, 128, 1024, (const float*)d_in[21], y_out);
}

// Round 12
// 6044.538 us; speedup vs baseline: 1.4968x; 1.0394x over previous
//
#include <hip/hip_runtime.h>

typedef unsigned short u16;
typedef unsigned int u32;
typedef unsigned long long u64;
typedef __bf16 bf16x8 __attribute__((ext_vector_type(8)));
typedef float f32x4 __attribute__((ext_vector_type(4)));

union FU { f32x4 f; bf16x8 h; };

__device__ __forceinline__ u16 f2b(float f) {
  unsigned u = __float_as_uint(f);
  return (u16)((u + 0x7fffu + ((u >> 16) & 1u)) >> 16);
}

// per-lane coherent 2B store (init only; cold path)
__device__ __forceinline__ void st_b16_llc(u16* p, u16 v) {
  __hip_atomic_store(p, v, __ATOMIC_RELAXED, __HIP_MEMORY_SCOPE_AGENT);
}

// plain coherent stores (wave-coalesced; no TCC atomic serialization)
__device__ __forceinline__ void st_u32_cc(u32* p, u32 v) {
  asm volatile("global_store_dword %0, %1, off sc0 sc1" :: "v"(p), "v"(v) : "memory");
}
__device__ __forceinline__ void st_u64_cc(void* p, u64 v) {
  asm volatile("global_store_dwordx2 %0, %1, off sc0 sc1" :: "v"(p), "v"(v) : "memory");
}

// coherent dword load (poll path; valid on return)
__device__ __forceinline__ u32 ld_dword_cc(const u32* p) {
  u32 v;
  asm volatile("global_load_dword %0, %1, off sc0 sc1\n\ts_waitcnt vmcnt(0)"
               : "=v"(v) : "v"(p) : "memory");
  return v;
}

// pack 4 neighboring lanes' bf16 into one u64 (lanes c15&3==0 hold cols +0..3)
// partners (xor 1, xor 2) stay inside the active 8-lane publish group.
__device__ __forceinline__ u64 pack4(u32 lo) {
  u32 p2 = lo | ((u32)__shfl_xor((int)lo, 1) << 16);
  return (u64)p2 | ((u64)(u32)__shfl_xor((int)p2, 2) << 32);
}

// issue 8 coherent 16B loads (covers 8 k-steps = 256 u16); valid after WAITV
#define ISSUE8CC(D, P)                                                       \
  asm volatile(                                                              \
      "global_load_dwordx4 %0, %8, off sc0 sc1\n\t"                          \
      "global_load_dwordx4 %1, %8, off offset:64 sc0 sc1\n\t"                \
      "global_load_dwordx4 %2, %8, off offset:128 sc0 sc1\n\t"               \
      "global_load_dwordx4 %3, %8, off offset:192 sc0 sc1\n\t"               \
      "global_load_dwordx4 %4, %8, off offset:256 sc0 sc1\n\t"               \
      "global_load_dwordx4 %5, %8, off offset:320 sc0 sc1\n\t"               \
      "global_load_dwordx4 %6, %8, off offset:384 sc0 sc1\n\t"               \
      "global_load_dwordx4 %7, %8, off offset:448 sc0 sc1"                   \
      : "=&v"((D)[0].f), "=&v"((D)[1].f), "=&v"((D)[2].f), "=&v"((D)[3].f),  \
        "=&v"((D)[4].f), "=&v"((D)[5].f), "=&v"((D)[6].f), "=&v"((D)[7].f)   \
      : "v"(P) : "memory")

// issue 4 cached 16B loads (read-only x data; counted in vmcnt like the rest)
#define ISSUE4C(D, P)                                                        \
  asm volatile(                                                              \
      "global_load_dwordx4 %0, %4, off\n\t"                                  \
      "global_load_dwordx4 %1, %4, off offset:64\n\t"                        \
      "global_load_dwordx4 %2, %4, off offset:128\n\t"                       \
      "global_load_dwordx4 %3, %4, off offset:192"                           \
      : "=&v"((D)[0].f), "=&v"((D)[1].f), "=&v"((D)[2].f), "=&v"((D)[3].f)   \
      : "v"(P) : "memory")

// counted wait + hard scheduling fence (rule #18: consumers stay below)
#define WAITV(N)                                                             \
  do {                                                                       \
    asm volatile("s_waitcnt vmcnt(" #N ")" ::: "memory");                    \
    __builtin_amdgcn_sched_barrier(0);                                       \
  } while (0)

// 8 MFMAs: A-frags from BUF, B-frags from LDS (zr layout / g layout)
#define MFMA8ZR(ACC, BUF, KSB)                                               \
  do {                                                                       \
    _Pragma("unroll") for (int j_ = 0; j_ < 8; ++j_)                         \
        ACC = __builtin_amdgcn_mfma_f32_16x16x32_bf16(                       \
            (BUF)[j_].h,                                                     \
            *(const bf16x8*)&zr_frag[(KSB + j_) * 512 + lane * 8],           \
            ACC, 0, 0, 0);                                                   \
  } while (0)
#define MFMA8G(ACC, BUF, KSB)                                                \
  do {                                                                       \
    _Pragma("unroll") for (int j_ = 0; j_ < 8; ++j_)                         \
        ACC = __builtin_amdgcn_mfma_f32_16x16x32_bf16(                       \
            (BUF)[j_].h,                                                     \
            *(const bf16x8*)&g_frag[(KSB + j_) * 256 + boff],                \
            ACC, 0, 0, 0);                                                   \
  } while (0)

// ---------------- generic fp32 -> bf16 cast ----------------
__global__ void cast_f32_bf16(const float* __restrict__ in, u16* __restrict__ out, int n) {
  int i = blockIdx.x * 256 + threadIdx.x;
  if (i < n) out[i] = f2b(in[i]);
}

// ---------------- tiled bf16 GEMM: C[M,N] = A[M,K] @ B[N,K]^T (fp32 out) ----------------
__global__ __launch_bounds__(256) void gemm_bt(
    const u16* __restrict__ A, const u16* __restrict__ B,
    int M, int N, int K,
    const float* __restrict__ bias, float* __restrict__ Cf)
{
  __shared__ u16 a_sm[128 * 32];
  __shared__ u16 b_sm[128 * 32];
  const int tid = threadIdx.x;
  const int lane = tid & 63;
  const int wid = tid >> 6;
  const int wm = wid >> 1, wn = wid & 1;
  const int m0 = blockIdx.x * 128, n0 = blockIdx.y * 128;
  const int q = lane >> 4, l15 = lane & 15, l3 = lane & 3;

  f32x4 acc[4][4];
  #pragma unroll
  for (int i = 0; i < 4; ++i)
    #pragma unroll
    for (int j = 0; j < 4; ++j) acc[i][j] = (f32x4){0.f, 0.f, 0.f, 0.f};

  for (int kk = 0; kk < K; kk += 32) {
    __syncthreads();
    #pragma unroll
    for (int p = 0; p < 2; ++p) {
      int idx = p * 256 + tid;
      int r = idx >> 2, cch = idx & 3;
      *(uint4*)&a_sm[r * 32 + ((cch ^ (r & 3)) * 8)] =
          *(const uint4*)&A[(size_t)(m0 + r) * K + kk + cch * 8];
      *(uint4*)&b_sm[r * 32 + ((cch ^ (r & 3)) * 8)] =
          *(const uint4*)&B[(size_t)(n0 + r) * K + kk + cch * 8];
    }
    __syncthreads();
    bf16x8 af[4], bfr[4];
    #pragma unroll
    for (int s = 0; s < 4; ++s) {
      int ra = wm * 64 + s * 16 + l15;
      af[s] = *(const bf16x8*)&a_sm[ra * 32 + ((q ^ l3) * 8)];
      int rb = wn * 64 + s * 16 + l15;
      bfr[s] = *(const bf16x8*)&b_sm[rb * 32 + ((q ^ l3) * 8)];
    }
    #pragma unroll
    for (int si = 0; si < 4; ++si)
      #pragma unroll
      for (int sj = 0; sj < 4; ++sj)
        acc[si][sj] = __builtin_amdgcn_mfma_f32_16x16x32_bf16(af[si], bfr[sj], acc[si][sj], 0, 0, 0);
  }

  #pragma unroll
  for (int si = 0; si < 4; ++si)
    #pragma unroll
    for (int sj = 0; sj < 4; ++sj)
      #pragma unroll
      for (int e = 0; e < 4; ++e) {
        int m = m0 + wm * 64 + si * 16 + q * 4 + e;
        int n = n0 + wn * 64 + sj * 16 + l15;
        Cf[(size_t)m * N + n] = acc[si][sj][e] + (bias ? bias[n] : 0.f);
      }
}

// ---------------- fused 2-layer pipelined GRU ----------------
// Best verified structure (r9, 5.95ms steady): grid 256, 192-thread blocks,
// waves 0-1 work, wave 2 of bid 0 is a dedicated aggregator for 4
// per-(layer x wave) barrier domains, publishing to 8 replicated flag lines.
// Payload: plain sc0/sc1 coherent 16B loads, 3 rotating 8-frag groups with
// counted vmcnt ladders; pack4 u64 h-publishes; L1 reads h0_s ONCE per step
// (ph0 pre-accumulates g's x-side a1g while hp frags are live).
// SESSION FLOOR: 1024 sequential device-wide h-exchanges x ~5.8us measured
// exchange latency. Sync-machinery falsification sweep complete (r3-r11):
// volume/atomics/hops/replicas/decoupling all null or regressions past this.
__global__ __launch_bounds__(192, 1) void gru_pipe(
    const u16* __restrict__ Wh0, const u16* __restrict__ Wx0,
    const u16* __restrict__ Wh1, const u16* __restrict__ Wx1,
    const float* __restrict__ bz0, const float* __restrict__ br0, const float* __restrict__ bg0,
    const float* __restrict__ bz1, const float* __restrict__ br1, const float* __restrict__ bg1,
    const u16* __restrict__ xb,                      // [32][512][128] bf16
    const float* __restrict__ h0p,                   // (32,2,1024) fp32
    u16* __restrict__ h0buf,                         // 2 x [32][1024] bf16 rotating
    u16* __restrict__ hb1,                           // [32][1024]
    u16* __restrict__ rh0b, u16* __restrict__ rh1b,  // [32][1024]
    u16* __restrict__ seq1,                          // [32][512][1024] bf16
    float* __restrict__ hid,                         // (32,2,1024) fp32 out
    u32* __restrict__ slots)                         // 512 wave slots + 8x32 lflags
{
  __shared__ u16 zr_frag[64 * 512];                  // 64 KB max (L1)
  __shared__ u16 g_frag[64 * 256];                   // 32 KB max

  const int tid = threadIdx.x;
  const int lane = tid & 63;
  const int w = tid >> 6;                            // 0,1 = worker; 2 = agg/idle
  const int bid = blockIdx.x;
  u32* lflags = slots + 512;

  const bool Lyr1 = bid >= 128;
  const int nb = (bid & 127) * 8;
  const int q = lane >> 4, c15 = lane & 15, nl = c15 & 7;
  const int n_own = nb + nl;
  const bool isz = c15 < 8;
  const int brow = w * 16 + c15;                     // A-fragment batch row
  const int boff = (q * 8 + nl) * 8;                 // g_frag B-fragment offset
  const int aoff = brow * 1024 + q * 8;              // A-fragment element offset
  const int KS = Lyr1 ? 64 : 36;                     // K-steps of 32
  const int IN = Lyr1 ? 1024 : 128;
  const u16* Wh = Lyr1 ? Wh1 : Wh0;
  const u16* Wx = Lyr1 ? Wx1 : Wx0;
  const size_t WXG = (size_t)1024 * IN;              // Wx per-gate elems

  const int d_own = (Lyr1 ? 2 : 0) | (w & 1);
  const int d_oth = (Lyr1 ? 0 : 2) | (w & 1);
  u32* slot_ptr = &slots[d_own * 128 + (bid & 127)];
  const int rrep = bid >> 5;                         // replica line 0..7
  const bool laneOth = (lane & 1) != 0;
  const u32* lfp = &lflags[rrep * 32 + (laneOth ? d_oth : d_own)];

  float hreg[4], zreg[4] = {0.f, 0.f, 0.f, 0.f};
  f32x4 a1g = {0.f, 0.f, 0.f, 0.f};                  // L1: g x-side carried ph0->ph1

  if (tid < 128) {
    // ---- stage concat [Wh | Wx] weights into LDS in MFMA B-frag order ----
    for (int cidx = tid; cidx < KS * 64; cidx += 128) {
      int ks = cidx >> 6, l = cidx & 63;
      int lq = l >> 4, lc = l & 15;
      int row = nb + (lc & 7), gate = (lc < 8) ? 0 : 1;  // z | r
      int k0 = ks * 32 + lq * 8;
      const u16* src = (k0 < 1024)
          ? Wh + (size_t)gate * 1048576 + (size_t)row * 1024 + k0
          : Wx + (size_t)gate * WXG + (size_t)row * IN + (k0 - 1024);
      *(uint4*)&zr_frag[cidx * 8] = *(const uint4*)src;
    }
    for (int gidx = tid; gidx < KS * 32; gidx += 128) {
      int ks = gidx >> 5, s = gidx & 31;
      int lq = s >> 3, r8 = s & 7;
      int row = nb + r8, k0 = ks * 32 + lq * 8;
      const u16* src = (k0 < 1024)
          ? Wh + (size_t)2 * 1048576 + (size_t)row * 1024 + k0
          : Wx + (size_t)2 * WXG + (size_t)row * IN + (k0 - 1024);
      *(uint4*)&g_frag[gidx * 8] = *(const uint4*)src;
    }
    // ---- init state: z-lanes hold h fp32; publish bf16 ----
    #pragma unroll
    for (int e = 0; e < 4; ++e) {
      int b = w * 16 + q * 4 + e;
      float v = h0p[b * 2048 + (Lyr1 ? 1024 : 0) + n_own];
      hreg[e] = v;
      if (isz)
        st_b16_llc((Lyr1 ? hb1 : h0buf + 32768) + b * 1024 + n_own, f2b(v));
    }
  }
  __syncthreads();                                   // all 3 waves; drains vmcnt

  // ---------- aggregator / idle third wave ----------
  if (w == 2) {
    if (bid == 0) {
      const u32* my = slots + lane * 8;              // 8 slots per lane = 512
      const int dgrp = lane >> 4;                    // domain this lane feeds
      u32 pub = 0;
      for (;;) {
        uint4 va, vb;
        asm volatile(
            "global_load_dwordx4 %0, %2, off sc0 sc1\n\t"
            "global_load_dwordx4 %1, %2, off offset:16 sc0 sc1\n\t"
            "s_waitcnt vmcnt(0)"
            : "=&v"(va), "=&v"(vb) : "v"(my) : "memory");
        u32 m = min(min(min(va.x, va.y), min(va.z, va.w)),
                    min(min(vb.x, vb.y), min(vb.z, vb.w)));
        m = min(m, (u32)__shfl_xor((int)m, 1));
        m = min(m, (u32)__shfl_xor((int)m, 2));
        m = min(m, (u32)__shfl_xor((int)m, 4));
        m = min(m, (u32)__shfl_xor((int)m, 8));
        if (m > pub) {
          pub = m;
          if ((lane & 15) == 0) {
            #pragma unroll
            for (int r = 0; r < 8; ++r) st_u32_cc(&lflags[r * 32 + dgrp], m);
          }
        }
        if (__all(pub >= 1026u)) break;
        __builtin_amdgcn_s_sleep(1);
      }
    }
    return;
  }

  // post init arrival (epoch 1) per wave
  if (lane == 0) st_u32_cc(slot_ptr, 1u);

  // ---- biases ----
  const float bias1 = isz ? (Lyr1 ? bz1 : bz0)[n_own] : (Lyr1 ? br1 : br0)[n_own];
  const float bias2 = (Lyr1 ? bg1 : bg0)[n_own];

  FU xfu[4];                                         // L0: x frags, live both phases
  FU sA[8], sB[8], sC[8];                            // rotating stream groups (96 VGPR)

  for (int p = 0; p < 1026; ++p) {
    const int t = p >> 1, ph = p & 1;

    // ---- entry wait (both waves poll; no intra-wg barriers in the loop) ----
    {
      const u32 tgt = laneOth ? ((Lyr1 && ph == 0) ? (u32)(p + 1) : (u32)p)
                              : (u32)(p + 1);
      for (;;) {
        u32 v = ld_dword_cc(lfp);
        if (__all(v >= tgt)) break;
        __builtin_amdgcn_s_sleep(1);
      }
    }

    if (!Lyr1) {
      if (t < 512) {
        f32x4 a0 = {0.f,0.f,0.f,0.f}, a1 = {0.f,0.f,0.f,0.f};
        if (ph == 0) {
          const u16* hp = h0buf + ((t - 1) & 1) * 32768 + aoff;
          const u16* xp = xb + ((size_t)brow * 512 + t) * 128 + q * 8;
          ISSUE4C(xfu, xp);                          // 4 out
          ISSUE8CC(sA, hp);                          // 12
          ISSUE8CC(sB, hp + 256);                    // 20
          ISSUE8CC(sC, hp + 512);                    // 28
          WAITV(16); MFMA8ZR(a0, sA, 0);             // xfu+sA done
          ISSUE8CC(sA, hp + 768);                    // 24
          WAITV(16); MFMA8ZR(a0, sB, 8);
          WAITV(8);  MFMA8ZR(a0, sC, 16);
          WAITV(0);  MFMA8ZR(a0, sA, 24);
          #pragma unroll
          for (int j = 0; j < 4; ++j)
            a1 = __builtin_amdgcn_mfma_f32_16x16x32_bf16(
                xfu[j].h, *(const bf16x8*)&zr_frag[(32 + j) * 512 + lane * 8], a1, 0, 0, 0);
          float hsh[4];
          #pragma unroll
          for (int e = 0; e < 4; ++e) hsh[e] = __shfl_xor(hreg[e], 8);
          #pragma unroll
          for (int e = 0; e < 4; ++e) {
            float pre = a0[e] + a1[e] + bias1;
            float s = 1.f / (1.f + __expf(-pre));
            if (isz) zreg[e] = s;
            else {
              u64 p4 = pack4((u32)f2b(s * hsh[e]));
              if ((c15 & 3) == 0)
                st_u64_cc(&rh0b[(w * 16 + q * 4 + e) * 1024 + nb + (c15 & 7)], p4);
            }
          }
        } else {
          const u16* rp = rh0b + aoff;
          ISSUE8CC(sA, rp);                          // 8
          ISSUE8CC(sB, rp + 256);                    // 16
          ISSUE8CC(sC, rp + 512);                    // 24
          WAITV(16); MFMA8G(a0, sA, 0);
          ISSUE8CC(sA, rp + 768);                    // 24
          WAITV(16); MFMA8G(a0, sB, 8);
          WAITV(8);  MFMA8G(a0, sC, 16);
          WAITV(0);  MFMA8G(a0, sA, 24);
          #pragma unroll
          for (int j = 0; j < 4; ++j)
            a1 = __builtin_amdgcn_mfma_f32_16x16x32_bf16(
                xfu[j].h, *(const bf16x8*)&g_frag[(32 + j) * 256 + boff], a1, 0, 0, 0);
          if (isz) {
            u16* hout = h0buf + (t & 1) * 32768;
            #pragma unroll
            for (int e = 0; e < 4; ++e) {
              int b = w * 16 + q * 4 + e;
              float pre = a0[e] + a1[e] + bias2;
              float ex = __expf(2.f * pre);
              float gv = 1.f - 2.f / (ex + 1.f);      // tanh, overflow-safe
              float hn = zreg[e] * hreg[e] + (1.f - zreg[e]) * gv;
              hreg[e] = hn;
              u64 p4 = pack4((u32)f2b(hn));
              if ((c15 & 3) == 0) st_u64_cc(&hout[b * 1024 + nb + c15], p4);
              if (t == 511) hid[b * 2048 + n_own] = hn;
            }
          }
        }
      }
    } else {
      if (t >= 1) {
        const int s = t - 1;
        f32x4 a0 = {0.f,0.f,0.f,0.f}, a1 = {0.f,0.f,0.f,0.f};
        if (ph == 0) {
          const u16* hp = h0buf + (s & 1) * 32768 + aoff;
          const u16* hb = hb1 + aoff;
          a1g = (f32x4){0.f, 0.f, 0.f, 0.f};
          ISSUE8CC(sA, hb);                          // 8
          ISSUE8CC(sB, hb + 256);                    // 16
          ISSUE8CC(sC, hb + 512);                    // 24
          WAITV(16); MFMA8ZR(a0, sA, 0);  ISSUE8CC(sA, hb + 768);   // 24
          WAITV(16); MFMA8ZR(a0, sB, 8);  ISSUE8CC(sB, hp);         // 24
          WAITV(16); MFMA8ZR(a0, sC, 16); ISSUE8CC(sC, hp + 256);   // 24
          WAITV(16); MFMA8ZR(a0, sA, 24); ISSUE8CC(sA, hp + 512);   // 24
          WAITV(16); MFMA8ZR(a1, sB, 32); MFMA8G(a1g, sB, 32);
                     ISSUE8CC(sB, hp + 768);                        // 24
          WAITV(16); MFMA8ZR(a1, sC, 40); MFMA8G(a1g, sC, 40);
          WAITV(8);  MFMA8ZR(a1, sA, 48); MFMA8G(a1g, sA, 48);
          WAITV(0);  MFMA8ZR(a1, sB, 56); MFMA8G(a1g, sB, 56);
          float hsh[4];
          #pragma unroll
          for (int e = 0; e < 4; ++e) hsh[e] = __shfl_xor(hreg[e], 8);
          #pragma unroll
          for (int e = 0; e < 4; ++e) {
            float pre = a0[e] + a1[e] + bias1;
            float sg = 1.f / (1.f + __expf(-pre));
            if (isz) zreg[e] = sg;
            else {
              u64 p4 = pack4((u32)f2b(sg * hsh[e]));
              if ((c15 & 3) == 0)
                st_u64_cc(&rh1b[(w * 16 + q * 4 + e) * 1024 + nb + (c15 & 7)], p4);
            }
          }
        } else {
          const u16* rp = rh1b + aoff;
          ISSUE8CC(sA, rp);                          // 8
          ISSUE8CC(sB, rp + 256);                    // 16
          ISSUE8CC(sC, rp + 512);                    // 24
          WAITV(16); MFMA8G(a0, sA, 0);
          ISSUE8CC(sA, rp + 768);                    // 24
          WAITV(16); MFMA8G(a0, sB, 8);
          WAITV(8);  MFMA8G(a0, sC, 16);
          WAITV(0);  MFMA8G(a0, sA, 24);
          if (isz) {
            #pragma unroll
            for (int e = 0; e < 4; ++e) {
              int b = w * 16 + q * 4 + e;
              float pre = a0[e] + a1g[e] + bias2;     // x-side pre-accumulated in ph0
              float ex = __expf(2.f * pre);
              float gv = 1.f - 2.f / (ex + 1.f);
              float hn = zreg[e] * hreg[e] + (1.f - zreg[e]) * gv;
              hreg[e] = hn;
              u64 p4 = pack4((u32)f2b(hn));
              if ((c15 & 3) == 0) {
                st_u64_cc(&hb1[b * 1024 + nb + c15], p4);
                *(u64*)&seq1[((size_t)b * 512 + s) * 1024 + nb + c15] = p4;
              }
              if (s == 511) hid[1024 + b * 2048 + n_own] = hn;
            }
          }
        }
      }
    }

    // ---- per-wave arrival (last interval posts nothing) ----
    if (p < 1025) {
      WAITV(0);                                      // drain this wave's stores
      if (lane == 0) st_u32_cc(slot_ptr, (u32)(p + 2));
    }
  }
}

// ---------------- host ----------------
extern "C" void kernel_launch(void* const* d_in, const int* in_sizes, int n_in,
                              void* d_out, int out_size, void* d_ws, size_t ws_size,
                              hipStream_t stream) {
  (void)in_sizes; (void)n_in; (void)out_size; (void)ws_size;
  char* ws = (char*)d_ws;
  const size_t MB = 1024ull * 1024ull;
  u16* seq1 = (u16*)(ws + 0);                         // 32 MB
  u16* xb   = (u16*)(ws + 32 * MB);                   // 4 MB
  u16* Wh0  = (u16*)(ws + 36 * MB);                   // 6 MB
  u16* Wh1  = (u16*)(ws + 42 * MB);                   // 6 MB
  u16* Wx0  = (u16*)(ws + 48 * MB);                   // 0.75 MB
  u16* Wx1  = (u16*)(ws + 49 * MB);                   // 6 MB
  u16* Wyb  = (u16*)(ws + 55 * MB);                   // 0.25 MB
  u16* h0buf = (u16*)(ws + 56 * MB);                  // 2 x 64 KB
  u16* hb1  = (u16*)(ws + 56 * MB + 128 * 1024);      // 64 KB
  u16* rh0b = (u16*)(ws + 56 * MB + 192 * 1024);      // 64 KB
  u16* rh1b = (u16*)(ws + 56 * MB + 256 * 1024);      // 64 KB
  u32* slots = (u32*)(ws + 56 * MB + 320 * 1024);     // 512 slots + 8x32 lflags

  hipMemsetAsync(slots, 0, 4096, stream);

  auto cast = [&](const void* in, u16* out, int n) {
    cast_f32_bf16<<<(n + 255) / 256, 256, 0, stream>>>((const float*)in, out, n);
  };
  cast(d_in[0], xb, 2097152);                               // x
  cast(d_in[3],  Wh0 + 0,       1048576);                   // Whz0
  cast(d_in[6],  Wh0 + 1048576, 1048576);                   // Whr0
  cast(d_in[9],  Wh0 + 2097152, 1048576);                   // Whg0
  cast(d_in[12], Wh1 + 0,       1048576);                   // Whz1
  cast(d_in[15], Wh1 + 1048576, 1048576);                   // Whr1
  cast(d_in[18], Wh1 + 2097152, 1048576);                   // Whg1
  cast(d_in[2],  Wx0 + 0,      131072);                     // Wxz0
  cast(d_in[5],  Wx0 + 131072, 131072);                     // Wxr0
  cast(d_in[8],  Wx0 + 262144, 131072);                     // Wxg0
  cast(d_in[11], Wx1 + 0,       1048576);                   // Wxz1
  cast(d_in[14], Wx1 + 1048576, 1048576);                   // Wxr1
  cast(d_in[17], Wx1 + 2097152, 1048576);                   // Wxg1
  cast(d_in[20], Wyb, 131072);                              // Wy

  float* y_out = (float*)d_out;
  float* hid = y_out + 2097152;                             // hidden (32,2,1024)

  gru_pipe<<<256, dim3(192), 0, stream>>>(
      Wh0, Wx0, Wh1, Wx1,
      (const float*)d_in[4],  (const float*)d_in[7],  (const float*)d_in[10],
      (const float*)d_in[13], (const float*)d_in[16], (const float*)d_in[19],
      xb, (const float*)d_in[1],
      h0buf, hb1, rh0b, rh1b, seq1, hid, slots);

  // output projection y = seq1 @ Wy^T + by  (M=16384, N=128, K=1024)
  gemm_bt<<<dim3(128, 1), dim3(256), 0, stream>>>(
      seq1, Wyb, 16384, 128, 1024, (const float*)d_in[21], y_out);
}